// Round 9
// baseline (201.112 us; speedup 1.0000x reference)
//
#include <hip/hip_runtime.h>
#include <stdint.h>

typedef short s16x8 __attribute__((ext_vector_type(8)));
typedef float f32x16 __attribute__((ext_vector_type(16)));
typedef unsigned int u32;
typedef unsigned int u32x2 __attribute__((ext_vector_type(2)));

#define NFRAG 336
#define WS_USHORTS (NFRAG*512)
#define PANEL_FRAGS 8
#define PANEL_BYTES (PANEL_FRAGS*1024)   // 8192
#define LDS_BYTES (3*PANEL_BYTES)        // 24576 — multiple of 8KB: no granule
                                         // rounding; 4+ blocks/CU by LDS.

#define MFMA(a,b,c) __builtin_amdgcn_mfma_f32_32x32x16_bf16((a),(b),(c),0,0,0)

__device__ __forceinline__ unsigned short f2bf(float f){
  u32 x = __builtin_bit_cast(u32, f);
  x += 0x7fffu + ((x >> 16) & 1u);   // RNE
  return (unsigned short)(x >> 16);
}

__device__ __forceinline__ float bfhi(float b){
  return __builtin_bit_cast(float, (u32)f2bf(b) << 16);
}

// hot-path pack: single HW instruction, RNE (T12 recipe; no builtin on gfx950)
__device__ __forceinline__ u32 pkbf(float a, float b){
  u32 r;
  asm("v_cvt_pk_bf16_f32 %0, %1, %2" : "=v"(r) : "v"(a), "v"(b));
  return r;
}

__device__ __forceinline__ float fast_tanh(float x){
  float ax = fabsf(x);
  float e = __expf(-2.0f * ax);
  float r = (1.0f - e) * __builtin_amdgcn_rcpf(1.0f + e);
  return x < 0.0f ? -r : r;
}

// cross-half sum. NOTE: do NOT use permlane32_swap(s,s) here — identical
// operands to the in-place two-address swap miscompiled (R1 failure).
__device__ __forceinline__ float halfsum(float s){
  return s + __shfl_xor(s, 32);
}

// D-tile (f32x16: 32 feats x 32 batch) -> two B-frags. permlane32_swap with
// DISTINCT operands (tied-operand hazard cannot occur) — 4 VALU swaps replace
// 8 ds_bpermute + 8 cndmask (R2: +8%).
__device__ __forceinline__ void tile2frags(const f32x16 v, s16x8& f0, s16x8& f1){
  u32 w00 = pkbf(v[0],  v[1]),  w01 = pkbf(v[2],  v[3]);
  u32 w10 = pkbf(v[4],  v[5]),  w11 = pkbf(v[6],  v[7]);
  u32 w20 = pkbf(v[8],  v[9]),  w21 = pkbf(v[10], v[11]);
  u32 w30 = pkbf(v[12], v[13]), w31 = pkbf(v[14], v[15]);
  u32x2 p0 = __builtin_amdgcn_permlane32_swap(w00, w10, false, false);
  u32x2 p1 = __builtin_amdgcn_permlane32_swap(w01, w11, false, false);
  u32x2 p2 = __builtin_amdgcn_permlane32_swap(w20, w30, false, false);
  u32x2 p3 = __builtin_amdgcn_permlane32_swap(w21, w31, false, false);
  int4 r0, r1;
  r0.x = (int)p0[0]; r0.y = (int)p1[0]; r0.z = (int)p0[1]; r0.w = (int)p1[1];
  r1.x = (int)p2[0]; r1.y = (int)p3[0]; r1.z = (int)p2[1]; r1.w = (int)p3[1];
  f0 = __builtin_bit_cast(s16x8, r0);
  f1 = __builtin_bit_cast(s16x8, r1);
}

// ============ weight pre-pack: frag-linear, consumption order, bias hi/lo k-cols ============
// [0,2) L1  [2,12) L2  [12,17) L3  [17,56) D1 (nt-major, 3 kf each)
// [56,336) 5 chunks x 56: r<52 -> D2 frag=kf*2+nt (kf 0..25), r>=52 -> D3 kt=4n+(r-52)
__global__ void wconv_kernel(const float* __restrict__ uw1, const float* __restrict__ ub1,
                             const float* __restrict__ uw2, const float* __restrict__ ub2,
                             const float* __restrict__ uw3, const float* __restrict__ ub3,
                             const float* __restrict__ dw1, const float* __restrict__ db1,
                             const float* __restrict__ dw2, const float* __restrict__ db2,
                             const float* __restrict__ dw3, const float* __restrict__ db3,
                             unsigned short* __restrict__ wp)
{
  int i = blockIdx.x*256 + threadIdx.x;
  if (i >= WS_USHORTS) return;
  int f    = i >> 9;
  int lane = (i >> 3) & 63;
  int j    = i & 7;
  int row  = lane & 31;
  int k8   = (lane >> 5)*8 + j;
  float v = 0.0f;
  if (f < 2){                                   // L1: [x12,u,b_hi,b_lo,0]
    int feat = f*32 + row; int k = k8;
    if (k < 13) v = uw1[feat*13 + k];
    else if (k == 13) v = ub1[feat];
    else if (k == 14) v = ub1[feat] - bfhi(ub1[feat]);
  } else if (f < 12){                           // L2: K=80, k64=b_hi, k65=b_lo
    int t = f - 2; int kt = t >> 1, nt = t & 1;
    int feat = nt*32 + row; int k = kt*16 + k8;
    if (k < 64) v = uw2[feat*128 + k];
    else if (k == 64) v = ub2[feat];
    else if (k == 65) v = ub2[feat] - bfhi(ub2[feat]);
  } else if (f < 17){                           // L3: K=80, k64/65 bias pair
    int kt = f - 12; int feat = row; int k = kt*16 + k8;
    if (k < 64) v = uw3[feat*64 + k];
    else if (k == 64) v = ub3[feat];
    else if (k == 65) v = ub3[feat] - bfhi(ub3[feat]);
  } else if (f < 56){                           // D1: [msg32,u,b_hi,b_lo], K=48
    int t = f - 17; int nt = t/3, kt = t%3;
    int feat = nt*32 + row; int k = kt*16 + k8;
    if (feat < 400){
      if (k < 33) v = dw1[feat*65 + k];
      else if (k == 33) v = db1[feat];
      else if (k == 34) v = db1[feat] - bfhi(db1[feat]);
    } else if ((feat == 400 || feat == 401) && k == 33) v = 1.0f; // h1[400]=h1[401]=1
  } else {                                      // D2/D3 interleaved chunks
    int t = f - 56; int n = t/56; int r = t%56;
    if (r < 52){                                // D2: feat=n*64+nt*32+row, k=kf*16+k8
      int kf = r >> 1, nt = r & 1;
      int feat = n*64 + nt*32 + row; int k = kf*16 + k8;
      if (feat < 300){
        if (k < 400) v = dw2[feat*400 + k];
        else if (k == 400) v = db2[feat];
        else if (k == 401) v = db2[feat] - bfhi(db2[feat]);
      } else if ((feat == 300 || feat == 301) && k == 400) v = 1.0f; // h2[300]=h2[301]=1
    } else {                                    // D3: kt = 4n + (r-52)
      int kt = n*4 + (r - 52); int feat = row; int k = kt*16 + k8;
      if (k < 300) v = dw3[feat*300 + k];
      else if (k == 300) v = db3[feat];
      else if (k == 301) v = db3[feat] - bfhi(db3[feat]);
    }
  }
  wp[i] = f2bf(v);
}

// ============ fused forward: 3-slot 8-frag ring, 42 panels, high residency ============
// Panel P = frags [8P, 8P+8), LDS slot P%3. LDS = 24576 B (multiple of 8KB ->
// no granule rounding) + ~120 VGPR + __launch_bounds__(256,4) aims at
// 4 blocks x 4 waves = 16 waves/CU: 4 independent barrier groups cover each
// other's barrier drains on the LDS port.
// BND(P): publish panel P (staged at BND(P-2)); stage P+2 into slot (P-1)%3
// (panel P-1 fully consumed in region [BND(P-1),BND(P)) by construction).
// R7's tail software-pipelining retained (retire stage-i epilogue VALU inside
// stage i+1's regions). All weights via LDS (direct loads dead: R6/R8).
__device__ __forceinline__ s16x8 fragF(const char* sm, int f, int ln){
  return *(const s16x8*)(sm + ((f/PANEL_FRAGS) % 3)*PANEL_BYTES
                            + (f % PANEL_FRAGS)*1024 + ln*16);
}

// exactly 2 global_load_lds per thread per panel (8KB / 256 thr / 16B)
__device__ __forceinline__ void stage8(const unsigned short* wp, char* sm, int panel, int tid){
  char* dst = sm + (panel % 3)*PANEL_BYTES;
  const char* src = (const char*)wp + (size_t)panel*PANEL_BYTES;
  #pragma unroll
  for (int j = 0; j < 2; ++j){
    int off = j*4096 + tid*16;
    __builtin_amdgcn_global_load_lds(
      (const __attribute__((address_space(1))) unsigned int*)(src + off),
      (__attribute__((address_space(3))) unsigned int*)(dst + off), 16, 0, 0);
  }
}

#define BND(P) { \
  __syncthreads(); \
  if ((P)+2 <= 41) stage8(wp, sm, (P)+2, tid); \
}

// relu in place + pack to two B-frags
#define TAIL1(aSrc, oA, oB) { \
  _Pragma("unroll") \
  for (int r = 0; r < 16; ++r) aSrc[r] = fmaxf(aSrc[r], 0.f); \
  tile2frags(aSrc, oA, oB); }

// 3 MFMAs of one D1 triple into acc (acc pre-zeroed)
#define D1MM(f0_, acc) { \
  __builtin_amdgcn_s_setprio(1); \
  acc = MFMA(fragF(sm, (f0_)+0, ln), mf0, acc); \
  acc = MFMA(fragF(sm, (f0_)+1, ln), mf1, acc); \
  acc = MFMA(fragF(sm, (f0_)+2, ln), mf2, acc); \
  __builtin_amdgcn_s_setprio(0); }

// D2 MFMA run [r0,r1) into named accumulators (LDS A-operand)
#define D2R(fb, r0, r1, A0, A1) { \
  __builtin_amdgcn_s_setprio(1); \
  _Pragma("unroll") \
  for (int r = (r0); r < (r1); ++r){ \
    s16x8 hb = h1f[r>>1]; \
    if (r & 1) A1 = MFMA(fragF(sm, (fb)+r, ln), hb, A1); \
    else       A0 = MFMA(fragF(sm, (fb)+r, ln), hb, A0); \
  } \
  __builtin_amdgcn_s_setprio(0); }

// pre-read D3 weight frags (fb+52..55) into regs inside their panel's region
#define LOADD3W(fb) { \
  d3w0 = fragF(sm, (fb)+52, ln); \
  d3w1 = fragF(sm, (fb)+53, ln); \
  d3w2 = fragF(sm, (fb)+54, ln); \
  d3w3 = fragF(sm, (fb)+55, ln); }

// deferred chunk tail pieces (spread across the next chunk's regions)
#define TAILD2_RELU(A0, A1) { \
  _Pragma("unroll") \
  for (int r = 0; r < 16; ++r){ \
    A0[r] = fmaxf(A0[r], 0.f); \
    A1[r] = fmaxf(A1[r], 0.f); \
  } }
#define TAILD2_CVT(A0, A1) { \
  tile2frags(A0, cT0, cT1); \
  tile2frags(A1, cT2, cT3); }
#define TAILD2_D3() { \
  __builtin_amdgcn_s_setprio(1); \
  acc3 = MFMA(d3w0, cT0, acc3); \
  acc3 = MFMA(d3w1, cT1, acc3); \
  acc3 = MFMA(d3w2, cT2, acc3); \
  acc3 = MFMA(d3w3, cT3, acc3); \
  __builtin_amdgcn_s_setprio(0); }

// chunk n>=1 (fb = 56+56n, multiple of 8): 7 boundaries, retire PRV's tail
#define CHUNKP(fb, P0, C0_, C1_, PR0, PR1) { \
  BND(P0) \
  C0_ = vzero; C1_ = vzero; \
  D2R(fb, 0, 8, C0_, C1_) \
  TAILD2_RELU(PR0, PR1) \
  BND((P0)+1) \
  D2R(fb, 8, 16, C0_, C1_) \
  TAILD2_CVT(PR0, PR1) \
  BND((P0)+2) \
  D2R(fb, 16, 24, C0_, C1_) \
  TAILD2_D3() \
  BND((P0)+3) \
  D2R(fb, 24, 32, C0_, C1_) \
  BND((P0)+4) \
  D2R(fb, 32, 40, C0_, C1_) \
  BND((P0)+5) \
  D2R(fb, 40, 48, C0_, C1_) \
  BND((P0)+6) \
  D2R(fb, 48, 52, C0_, C1_) \
  LOADD3W(fb) \
}

__global__ __launch_bounds__(256, 4) void fused_kernel(
    const float* __restrict__ state, const float* __restrict__ action,
    const unsigned short* __restrict__ wp, float* __restrict__ out)
{
  __shared__ __align__(1024) char sm[LDS_BYTES];

  const int tid = threadIdx.x;
  const int ln  = tid & 63;
  const int wid = tid >> 6;
  const int c   = ln & 31;          // batch col within wave
  const int h   = ln >> 5;          // lane half
  const int rowb = blockIdx.x*128 + wid*32;

  const f32x16 vzero = {};

  // ---- issue x/u loads (latency hides under P0/P1 staging) ----
  const float* xr = state + (size_t)(rowb + c)*12;
  float u = action[rowb + c];
  float4 xa, xbr;
  if (h == 0){
    xa  = *(const float4*)xr;
    xbr = *(const float4*)(xr + 4);
  } else {
    xa  = *(const float4*)(xr + 8);
  }

  stage8(wp, sm, 0, tid);
  stage8(wp, sm, 1, tid);
  BND(0)                                // publish P0+P1; stage P2

  // ---- pack constants (overlaps P2 staging) ----
  float4 xb = (h == 0) ? xbr : float4{u, 1.0f, 1.0f, 0.0f}; // k12=u, k13/14 bias carriers
  int4 xw;
  xw.x = pkbf(xa.x, xa.y); xw.y = pkbf(xa.z, xa.w);
  xw.z = pkbf(xb.x, xb.y); xw.w = pkbf(xb.z, xb.w);
  s16x8 xfrag = __builtin_bit_cast(s16x8, xw);
  int4 ow = {0,0,0,0}; if (h == 0) ow.x = 0x3F803F80;   // k64=1, k65=1
  s16x8 onef = __builtin_bit_cast(s16x8, ow);
  int4 mw = {0,0,0,0};
  if (h == 0){ mw.x = pkbf(u, 1.0f); mw.y = 0x3F80; }   // k32=u, k33=1, k34=1
  s16x8 mf2 = __builtin_bit_cast(s16x8, mw);

  // ======== C0: up-net (frags 0..16); boundaries F=8 (mid-L2), F=16 (mid-L3) ========
  s16x8 mf0, mf1;
  {
    s16x8 xf0, xf1, xf2, xf3, tf0, tf1, tf2, tf3;
    {
      f32x16 a0 = {}, a1 = {};
      a0 = MFMA(fragF(sm, 0, ln), xfrag, a0);
      a1 = MFMA(fragF(sm, 1, ln), xfrag, a1);
      float s = 0.f;
      #pragma unroll
      for (int r = 0; r < 16; ++r) s += a0[r]*a0[r] + a1[r]*a1[r];
      s = halfsum(s);
      float inv = __builtin_amdgcn_rsqf(fmaxf(s, 1e-24f));
      #pragma unroll
      for (int r = 0; r < 16; ++r){
        a0[r] = fast_tanh(a0[r]*inv);
        a1[r] = fast_tanh(a1[r]*inv);
      }
      tile2frags(a0, xf0, xf1);
      tile2frags(a1, xf2, xf3);
    }
    {
      f32x16 a0 = {}, a1 = {};
      __builtin_amdgcn_s_setprio(1);
      a0 = MFMA(fragF(sm, 2, ln), xf0, a0);  a1 = MFMA(fragF(sm, 3, ln), xf0, a1);
      a0 = MFMA(fragF(sm, 4, ln), xf1, a0);  a1 = MFMA(fragF(sm, 5, ln), xf1, a1);
      a0 = MFMA(fragF(sm, 6, ln), xf2, a0);  a1 = MFMA(fragF(sm, 7, ln), xf2, a1);
      __builtin_amdgcn_s_setprio(0);
      BND(1)                            // F=8: publish P1; stage P3
      __builtin_amdgcn_s_setprio(1);
      a0 = MFMA(fragF(sm, 8, ln), xf3, a0);  a1 = MFMA(fragF(sm, 9, ln), xf3, a1);
      a0 = MFMA(fragF(sm,10, ln), onef, a0); a1 = MFMA(fragF(sm,11, ln), onef, a1);
      __builtin_amdgcn_s_setprio(0);
      #pragma unroll
      for (int r = 0; r < 16; ++r){
        a0[r] = fast_tanh(a0[r]);
        a1[r] = fast_tanh(a1[r]);
      }
      tile2frags(a0, tf0, tf1);
      tile2frags(a1, tf2, tf3);
    }
    {
      f32x16 m = {};
      __builtin_amdgcn_s_setprio(1);
      m = MFMA(fragF(sm,12, ln), tf0, m);
      m = MFMA(fragF(sm,13, ln), tf1, m);
      m = MFMA(fragF(sm,14, ln), tf2, m);
      m = MFMA(fragF(sm,15, ln), tf3, m);
      __builtin_amdgcn_s_setprio(0);
      BND(2)                            // F=16: publish P2; stage P4
      __builtin_amdgcn_s_setprio(1);
      m = MFMA(fragF(sm,16, ln), onef, m);
      __builtin_amdgcn_s_setprio(0);
      float s = 0.f;
      #pragma unroll
      for (int r = 0; r < 16; ++r) s += m[r]*m[r];
      s = halfsum(s);
      float inv = __builtin_amdgcn_rsqf(fmaxf(s, 1e-24f));
      #pragma unroll
      for (int r = 0; r < 16; ++r) m[r] *= inv;
      tile2frags(m, mf0, mf1);
    }
  }

  // ======== D1: 13 triples (frags 17..55), tail-pipelined via aX/aY ========
  // Boundaries before frags 24 (straddle t23), 32 (clean), 40 (straddle t38),
  // 48 (straddle t47).
  s16x8 h1f[26];
  f32x16 aX = vzero, aY = vzero;
  D1MM(17, aX)
  D1MM(20, aY)  TAIL1(aX, h1f[0],  h1f[1])
  aX = vzero;                         // triple (23,24,25) straddles F=24
  __builtin_amdgcn_s_setprio(1);
  aX = MFMA(fragF(sm, 23, ln), mf0, aX);
  __builtin_amdgcn_s_setprio(0);
  BND(3)                              // F=24: stage P5
  __builtin_amdgcn_s_setprio(1);
  aX = MFMA(fragF(sm, 24, ln), mf1, aX);
  aX = MFMA(fragF(sm, 25, ln), mf2, aX);
  __builtin_amdgcn_s_setprio(0);
  TAIL1(aY, h1f[2], h1f[3])
  aY = vzero; D1MM(26, aY)  TAIL1(aX, h1f[4],  h1f[5])
  aX = vzero; D1MM(29, aX)  TAIL1(aY, h1f[6],  h1f[7])
  BND(4)                              // F=32 (clean, between triples): stage P6
  aY = vzero; D1MM(32, aY)  TAIL1(aX, h1f[8],  h1f[9])
  aX = vzero; D1MM(35, aX)  TAIL1(aY, h1f[10], h1f[11])
  aY = vzero;                         // triple (38,39,40) straddles F=40
  __builtin_amdgcn_s_setprio(1);
  aY = MFMA(fragF(sm, 38, ln), mf0, aY);
  aY = MFMA(fragF(sm, 39, ln), mf1, aY);
  __builtin_amdgcn_s_setprio(0);
  BND(5)                              // F=40: stage P7
  __builtin_amdgcn_s_setprio(1);
  aY = MFMA(fragF(sm, 40, ln), mf2, aY);
  __builtin_amdgcn_s_setprio(0);
  TAIL1(aX, h1f[12], h1f[13])
  aX = vzero; D1MM(41, aX)  TAIL1(aY, h1f[14], h1f[15])
  aY = vzero; D1MM(44, aY)  TAIL1(aX, h1f[16], h1f[17])
  aX = vzero;                         // triple (47,48,49) straddles F=48
  __builtin_amdgcn_s_setprio(1);
  aX = MFMA(fragF(sm, 47, ln), mf0, aX);
  __builtin_amdgcn_s_setprio(0);
  BND(6)                              // F=48: stage P8
  __builtin_amdgcn_s_setprio(1);
  aX = MFMA(fragF(sm, 48, ln), mf1, aX);
  aX = MFMA(fragF(sm, 49, ln), mf2, aX);
  __builtin_amdgcn_s_setprio(0);
  TAIL1(aY, h1f[18], h1f[19])
  aY = vzero; D1MM(50, aY)  TAIL1(aX, h1f[20], h1f[21])
  aX = vzero; D1MM(53, aX)  TAIL1(aY, h1f[22], h1f[23])
  // aX = triple 53; its tail (h1f[24],h1f[25]) retires inside chunk0's run0
  // (consumed only at chunk r>=48).

  // ======== D2/D3 chunks (frags 56..335); chunk n: P0 = 7+7n ========
  f32x16 acc3 = vzero;
  f32x16 dA0, dA1, dB0, dB1;
  s16x8 d3w0, d3w1, d3w2, d3w3, cT0, cT1, cT2, cT3;

  {                                   // chunk0 (fb=56, P0=7) -> dA
    BND(7)
    dA0 = vzero; dA1 = vzero;
    D2R(56, 0, 8, dA0, dA1)
    TAIL1(aX, h1f[24], h1f[25])
    BND(8)
    D2R(56, 8, 16, dA0, dA1)
    BND(9)
    D2R(56, 16, 24, dA0, dA1)
    BND(10)
    D2R(56, 24, 32, dA0, dA1)
    BND(11)
    D2R(56, 32, 40, dA0, dA1)
    BND(12)
    D2R(56, 40, 48, dA0, dA1)
    BND(13)
    D2R(56, 48, 52, dA0, dA1)
    LOADD3W(56)
  }
  CHUNKP(112, 14, dB0, dB1, dA0, dA1)   // chunk1 -> dB; retires chunk0 (dA)
  CHUNKP(168, 21, dA0, dA1, dB0, dB1)   // chunk2 -> dA; retires chunk1 (dB)
  CHUNKP(224, 28, dB0, dB1, dA0, dA1)   // chunk3 -> dB; retires chunk2 (dA)
  CHUNKP(280, 35, dA0, dA1, dB0, dB1)   // chunk4 -> dA; retires chunk3 (dB)
  // final tail: chunk4 (dA), exposed once
  TAILD2_RELU(dA0, dA1)
  TAILD2_CVT(dA0, dA1)
  TAILD2_D3()

  // ---- store: lane (h,c): feat block 8p+4h, regs 4p..4p+3 ----
  float* op = out + (size_t)(rowb + c)*32;
  #pragma unroll
  for (int p = 0; p < 4; ++p){
    float4 v4 = {acc3[4*p+0], acc3[4*p+1], acc3[4*p+2], acc3[4*p+3]};
    *(float4*)(op + p*8 + h*4) = v4;
  }
}

extern "C" void kernel_launch(void* const* d_in, const int* in_sizes, int n_in,
                              void* d_out, int out_size, void* d_ws, size_t ws_size,
                              hipStream_t stream)
{
  const float* state  = (const float*)d_in[0];
  const float* action = (const float*)d_in[1];
  const float* up_w1  = (const float*)d_in[2];
  const float* up_b1  = (const float*)d_in[3];
  const float* up_w2  = (const float*)d_in[4];
  const float* up_b2  = (const float*)d_in[5];
  const float* up_w3  = (const float*)d_in[6];
  const float* up_b3  = (const float*)d_in[7];
  const float* dyn_w1 = (const float*)d_in[8];
  const float* dyn_b1 = (const float*)d_in[9];
  const float* dyn_w2 = (const float*)d_in[10];
  const float* dyn_b2 = (const float*)d_in[11];
  const float* dyn_w3 = (const float*)d_in[12];
  const float* dyn_b3 = (const float*)d_in[13];
  unsigned short* wp = (unsigned short*)d_ws;

  hipLaunchKernelGGL(wconv_kernel, dim3((WS_USHORTS + 255)/256), dim3(256), 0, stream,
                     up_w1, up_b1, up_w2, up_b2, up_w3, up_b3,
                     dyn_w1, dyn_b1, dyn_w2, dyn_b2, dyn_w3, dyn_b3, wp);
  hipLaunchKernelGGL(fused_kernel, dim3(262144/128), dim3(256), 0, stream,
                     state, action, wp, (float*)d_out);
}

// Round 10
// 115.877 us; speedup vs baseline: 1.7356x; 1.7356x over previous
//
#include <hip/hip_runtime.h>
#include <stdint.h>

typedef short s16x8 __attribute__((ext_vector_type(8)));
typedef float f32x16 __attribute__((ext_vector_type(16)));
typedef unsigned int u32;
typedef unsigned int u32x2 __attribute__((ext_vector_type(2)));

#define NFRAG 336
#define WS_USHORTS (NFRAG*512)
#define PANEL_FRAGS 8
#define PANEL_BYTES (PANEL_FRAGS*1024)   // 8192
#define LDS_BYTES (3*PANEL_BYTES)        // 24576 — packs 3+ blocks/CU (proven R9)

#define MFMA(a,b,c) __builtin_amdgcn_mfma_f32_32x32x16_bf16((a),(b),(c),0,0,0)

__device__ __forceinline__ unsigned short f2bf(float f){
  u32 x = __builtin_bit_cast(u32, f);
  x += 0x7fffu + ((x >> 16) & 1u);   // RNE
  return (unsigned short)(x >> 16);
}

__device__ __forceinline__ float bfhi(float b){
  return __builtin_bit_cast(float, (u32)f2bf(b) << 16);
}

// hot-path pack: single HW instruction, RNE (T12 recipe; no builtin on gfx950)
__device__ __forceinline__ u32 pkbf(float a, float b){
  u32 r;
  asm("v_cvt_pk_bf16_f32 %0, %1, %2" : "=v"(r) : "v"(a), "v"(b));
  return r;
}

__device__ __forceinline__ float fast_tanh(float x){
  float ax = fabsf(x);
  float e = __expf(-2.0f * ax);
  float r = (1.0f - e) * __builtin_amdgcn_rcpf(1.0f + e);
  return x < 0.0f ? -r : r;
}

// cross-half sum. NOTE: do NOT use permlane32_swap(s,s) here — identical
// operands to the in-place two-address swap miscompiled (R1 failure).
__device__ __forceinline__ float halfsum(float s){
  return s + __shfl_xor(s, 32);
}

// D-tile (f32x16: 32 feats x 32 batch) -> two B-frags. permlane32_swap with
// DISTINCT operands (tied-operand hazard cannot occur) — 4 VALU swaps replace
// 8 ds_bpermute + 8 cndmask (R2: +8%).
__device__ __forceinline__ void tile2frags(const f32x16 v, s16x8& f0, s16x8& f1){
  u32 w00 = pkbf(v[0],  v[1]),  w01 = pkbf(v[2],  v[3]);
  u32 w10 = pkbf(v[4],  v[5]),  w11 = pkbf(v[6],  v[7]);
  u32 w20 = pkbf(v[8],  v[9]),  w21 = pkbf(v[10], v[11]);
  u32 w30 = pkbf(v[12], v[13]), w31 = pkbf(v[14], v[15]);
  u32x2 p0 = __builtin_amdgcn_permlane32_swap(w00, w10, false, false);
  u32x2 p1 = __builtin_amdgcn_permlane32_swap(w01, w11, false, false);
  u32x2 p2 = __builtin_amdgcn_permlane32_swap(w20, w30, false, false);
  u32x2 p3 = __builtin_amdgcn_permlane32_swap(w21, w31, false, false);
  int4 r0, r1;
  r0.x = (int)p0[0]; r0.y = (int)p1[0]; r0.z = (int)p0[1]; r0.w = (int)p1[1];
  r1.x = (int)p2[0]; r1.y = (int)p3[0]; r1.z = (int)p2[1]; r1.w = (int)p3[1];
  f0 = __builtin_bit_cast(s16x8, r0);
  f1 = __builtin_bit_cast(s16x8, r1);
}

// ============ weight pre-pack: frag-linear, consumption order, bias hi/lo k-cols ============
// [0,2) L1  [2,12) L2  [12,17) L3  [17,56) D1 (nt-major, 3 kf each)
// [56,336) 5 chunks x 56: r<52 -> D2 frag=kf*2+nt (kf 0..25), r>=52 -> D3 kt=4n+(r-52)
__global__ void wconv_kernel(const float* __restrict__ uw1, const float* __restrict__ ub1,
                             const float* __restrict__ uw2, const float* __restrict__ ub2,
                             const float* __restrict__ uw3, const float* __restrict__ ub3,
                             const float* __restrict__ dw1, const float* __restrict__ db1,
                             const float* __restrict__ dw2, const float* __restrict__ db2,
                             const float* __restrict__ dw3, const float* __restrict__ db3,
                             unsigned short* __restrict__ wp)
{
  int i = blockIdx.x*256 + threadIdx.x;
  if (i >= WS_USHORTS) return;
  int f    = i >> 9;
  int lane = (i >> 3) & 63;
  int j    = i & 7;
  int row  = lane & 31;
  int k8   = (lane >> 5)*8 + j;
  float v = 0.0f;
  if (f < 2){                                   // L1: [x12,u,b_hi,b_lo,0]
    int feat = f*32 + row; int k = k8;
    if (k < 13) v = uw1[feat*13 + k];
    else if (k == 13) v = ub1[feat];
    else if (k == 14) v = ub1[feat] - bfhi(ub1[feat]);
  } else if (f < 12){                           // L2: K=80, k64=b_hi, k65=b_lo
    int t = f - 2; int kt = t >> 1, nt = t & 1;
    int feat = nt*32 + row; int k = kt*16 + k8;
    if (k < 64) v = uw2[feat*128 + k];
    else if (k == 64) v = ub2[feat];
    else if (k == 65) v = ub2[feat] - bfhi(ub2[feat]);
  } else if (f < 17){                           // L3: K=80, k64/65 bias pair
    int kt = f - 12; int feat = row; int k = kt*16 + k8;
    if (k < 64) v = uw3[feat*64 + k];
    else if (k == 64) v = ub3[feat];
    else if (k == 65) v = ub3[feat] - bfhi(ub3[feat]);
  } else if (f < 56){                           // D1: [msg32,u,b_hi,b_lo], K=48
    int t = f - 17; int nt = t/3, kt = t%3;
    int feat = nt*32 + row; int k = kt*16 + k8;
    if (feat < 400){
      if (k < 33) v = dw1[feat*65 + k];
      else if (k == 33) v = db1[feat];
      else if (k == 34) v = db1[feat] - bfhi(db1[feat]);
    } else if ((feat == 400 || feat == 401) && k == 33) v = 1.0f; // h1[400]=h1[401]=1
  } else {                                      // D2/D3 interleaved chunks
    int t = f - 56; int n = t/56; int r = t%56;
    if (r < 52){                                // D2: feat=n*64+nt*32+row, k=kf*16+k8
      int kf = r >> 1, nt = r & 1;
      int feat = n*64 + nt*32 + row; int k = kf*16 + k8;
      if (feat < 300){
        if (k < 400) v = dw2[feat*400 + k];
        else if (k == 400) v = db2[feat];
        else if (k == 401) v = db2[feat] - bfhi(db2[feat]);
      } else if ((feat == 300 || feat == 301) && k == 400) v = 1.0f; // h2[300]=h2[301]=1
    } else {                                    // D3: kt = 4n + (r-52)
      int kt = n*4 + (r - 52); int feat = row; int k = kt*16 + k8;
      if (k < 300) v = dw3[feat*300 + k];
      else if (k == 300) v = db3[feat];
      else if (k == 301) v = db3[feat] - bfhi(db3[feat]);
    }
  }
  wp[i] = f2bf(v);
}

// ============ fused forward: 3-slot 8-frag ring, minimal register state ============
// Panel P = frags [8P, 8P+8), LDS slot P%3; 42 panels. BND(P): publish panel P
// (staged at BND(P-2)); stage P+2 into slot (P-1)%3 (panel P-1 consumed in the
// region just ended). Register diet vs R7: exposed tails (no dB/d3w/cT state),
// single D1 accumulator, h1f[25] replaced by the constant onef frag (tile
// nt=12 upper half = feats 400..415 = (1,1,0,..,0) for every batch).
// Goal: total VGPR+AGPR <= 170 -> 3 blocks/CU under __launch_bounds__(256,3).
__device__ __forceinline__ s16x8 fragF(const char* sm, int f, int ln){
  return *(const s16x8*)(sm + ((f/PANEL_FRAGS) % 3)*PANEL_BYTES
                            + (f % PANEL_FRAGS)*1024 + ln*16);
}

// exactly 2 global_load_lds per thread per panel (8KB / 256 thr / 16B)
__device__ __forceinline__ void stage8(const unsigned short* wp, char* sm, int panel, int tid){
  char* dst = sm + (panel % 3)*PANEL_BYTES;
  const char* src = (const char*)wp + (size_t)panel*PANEL_BYTES;
  #pragma unroll
  for (int j = 0; j < 2; ++j){
    int off = j*4096 + tid*16;
    __builtin_amdgcn_global_load_lds(
      (const __attribute__((address_space(1))) unsigned int*)(src + off),
      (__attribute__((address_space(3))) unsigned int*)(dst + off), 16, 0, 0);
  }
}

#define BND(P) { \
  __syncthreads(); \
  if ((P)+2 <= 41) stage8(wp, sm, (P)+2, tid); \
}

// relu in place + pack to two B-frags
#define TAIL1(aSrc, oA, oB) { \
  _Pragma("unroll") \
  for (int r = 0; r < 16; ++r) aSrc[r] = fmaxf(aSrc[r], 0.f); \
  tile2frags(aSrc, oA, oB); }

// 3 MFMAs of one D1 triple into acc (acc pre-zeroed)
#define D1MM(f0_, acc) { \
  __builtin_amdgcn_s_setprio(1); \
  acc = MFMA(fragF(sm, (f0_)+0, ln), mf0, acc); \
  acc = MFMA(fragF(sm, (f0_)+1, ln), mf1, acc); \
  acc = MFMA(fragF(sm, (f0_)+2, ln), mf2, acc); \
  __builtin_amdgcn_s_setprio(0); }

// D2 MFMA run [r0,r1); kf==25 uses the constant onef frag (== h1 feats 400..415)
#define D2R(fb, r0, r1) { \
  __builtin_amdgcn_s_setprio(1); \
  _Pragma("unroll") \
  for (int r = (r0); r < (r1); ++r){ \
    s16x8 hb = ((r>>1) == 25) ? onef : h1f[r>>1]; \
    if (r & 1) d2a1 = MFMA(fragF(sm, (fb)+r, ln), hb, d2a1); \
    else       d2a0 = MFMA(fragF(sm, (fb)+r, ln), hb, d2a0); \
  } \
  __builtin_amdgcn_s_setprio(0); }

// chunk n (fb = 56+56n, P0 = 7+7n): 7 regions; panel 13+7n holds frags
// fb+48..fb+55, so the D2 tail (relu+cvt) and all 4 D3 MFMAs run inside the
// last region with no cross-boundary state.
#define CHUNKS(fb, P0) { \
  BND(P0) \
  d2a0 = vzero; d2a1 = vzero; \
  D2R(fb, 0, 8) \
  BND((P0)+1) \
  D2R(fb, 8, 16) \
  BND((P0)+2) \
  D2R(fb, 16, 24) \
  BND((P0)+3) \
  D2R(fb, 24, 32) \
  BND((P0)+4) \
  D2R(fb, 32, 40) \
  BND((P0)+5) \
  D2R(fb, 40, 48) \
  BND((P0)+6) \
  D2R(fb, 48, 52) \
  { \
    _Pragma("unroll") \
    for (int r = 0; r < 16; ++r){ \
      d2a0[r] = fmaxf(d2a0[r], 0.f); \
      d2a1[r] = fmaxf(d2a1[r], 0.f); \
    } \
    s16x8 c0, c1, c2, c3; \
    tile2frags(d2a0, c0, c1); \
    tile2frags(d2a1, c2, c3); \
    __builtin_amdgcn_s_setprio(1); \
    acc3 = MFMA(fragF(sm, (fb)+52, ln), c0, acc3); \
    acc3 = MFMA(fragF(sm, (fb)+53, ln), c1, acc3); \
    acc3 = MFMA(fragF(sm, (fb)+54, ln), c2, acc3); \
    acc3 = MFMA(fragF(sm, (fb)+55, ln), c3, acc3); \
    __builtin_amdgcn_s_setprio(0); \
  } \
}

__global__ __launch_bounds__(256, 3) void fused_kernel(
    const float* __restrict__ state, const float* __restrict__ action,
    const unsigned short* __restrict__ wp, float* __restrict__ out)
{
  __shared__ __align__(1024) char sm[LDS_BYTES];

  const int tid = threadIdx.x;
  const int ln  = tid & 63;
  const int wid = tid >> 6;
  const int c   = ln & 31;          // batch col within wave
  const int h   = ln >> 5;          // lane half
  const int rowb = blockIdx.x*128 + wid*32;

  const f32x16 vzero = {};

  // ---- issue x/u loads (latency hides under P0/P1 staging) ----
  const float* xr = state + (size_t)(rowb + c)*12;
  float u = action[rowb + c];
  float4 xa, xbr;
  if (h == 0){
    xa  = *(const float4*)xr;
    xbr = *(const float4*)(xr + 4);
  } else {
    xa  = *(const float4*)(xr + 8);
  }

  stage8(wp, sm, 0, tid);
  stage8(wp, sm, 1, tid);
  BND(0)                                // publish P0+P1; stage P2

  // ---- pack constants (overlaps P2 staging) ----
  float4 xb = (h == 0) ? xbr : float4{u, 1.0f, 1.0f, 0.0f}; // k12=u, k13/14 bias carriers
  int4 xw;
  xw.x = pkbf(xa.x, xa.y); xw.y = pkbf(xa.z, xa.w);
  xw.z = pkbf(xb.x, xb.y); xw.w = pkbf(xb.z, xb.w);
  s16x8 xfrag = __builtin_bit_cast(s16x8, xw);
  int4 ow = {0,0,0,0}; if (h == 0) ow.x = 0x3F803F80;   // slots j=0,1 @ h=0
  s16x8 onef = __builtin_bit_cast(s16x8, ow);
  int4 mw = {0,0,0,0};
  if (h == 0){ mw.x = pkbf(u, 1.0f); mw.y = 0x3F80; }   // k32=u, k33=1, k34=1
  s16x8 mf2 = __builtin_bit_cast(s16x8, mw);

  // ======== C0: up-net (frags 0..16); boundaries F=8 (mid-L2), F=16 (mid-L3) ========
  s16x8 mf0, mf1;
  {
    s16x8 xf0, xf1, xf2, xf3, tf0, tf1, tf2, tf3;
    {
      f32x16 a0 = {}, a1 = {};
      a0 = MFMA(fragF(sm, 0, ln), xfrag, a0);
      a1 = MFMA(fragF(sm, 1, ln), xfrag, a1);
      float s = 0.f;
      #pragma unroll
      for (int r = 0; r < 16; ++r) s += a0[r]*a0[r] + a1[r]*a1[r];
      s = halfsum(s);
      float inv = __builtin_amdgcn_rsqf(fmaxf(s, 1e-24f));
      #pragma unroll
      for (int r = 0; r < 16; ++r){
        a0[r] = fast_tanh(a0[r]*inv);
        a1[r] = fast_tanh(a1[r]*inv);
      }
      tile2frags(a0, xf0, xf1);
      tile2frags(a1, xf2, xf3);
    }
    {
      f32x16 a0 = {}, a1 = {};
      __builtin_amdgcn_s_setprio(1);
      a0 = MFMA(fragF(sm, 2, ln), xf0, a0);  a1 = MFMA(fragF(sm, 3, ln), xf0, a1);
      a0 = MFMA(fragF(sm, 4, ln), xf1, a0);  a1 = MFMA(fragF(sm, 5, ln), xf1, a1);
      a0 = MFMA(fragF(sm, 6, ln), xf2, a0);  a1 = MFMA(fragF(sm, 7, ln), xf2, a1);
      __builtin_amdgcn_s_setprio(0);
      BND(1)                            // F=8: publish P1; stage P3
      __builtin_amdgcn_s_setprio(1);
      a0 = MFMA(fragF(sm, 8, ln), xf3, a0);  a1 = MFMA(fragF(sm, 9, ln), xf3, a1);
      a0 = MFMA(fragF(sm,10, ln), onef, a0); a1 = MFMA(fragF(sm,11, ln), onef, a1);
      __builtin_amdgcn_s_setprio(0);
      #pragma unroll
      for (int r = 0; r < 16; ++r){
        a0[r] = fast_tanh(a0[r]);
        a1[r] = fast_tanh(a1[r]);
      }
      tile2frags(a0, tf0, tf1);
      tile2frags(a1, tf2, tf3);
    }
    {
      f32x16 m = {};
      __builtin_amdgcn_s_setprio(1);
      m = MFMA(fragF(sm,12, ln), tf0, m);
      m = MFMA(fragF(sm,13, ln), tf1, m);
      m = MFMA(fragF(sm,14, ln), tf2, m);
      m = MFMA(fragF(sm,15, ln), tf3, m);
      __builtin_amdgcn_s_setprio(0);
      BND(2)                            // F=16: publish P2; stage P4
      __builtin_amdgcn_s_setprio(1);
      m = MFMA(fragF(sm,16, ln), onef, m);
      __builtin_amdgcn_s_setprio(0);
      float s = 0.f;
      #pragma unroll
      for (int r = 0; r < 16; ++r) s += m[r]*m[r];
      s = halfsum(s);
      float inv = __builtin_amdgcn_rsqf(fmaxf(s, 1e-24f));
      #pragma unroll
      for (int r = 0; r < 16; ++r) m[r] *= inv;
      tile2frags(m, mf0, mf1);
    }
  }

  // ======== D1: 13 triples (frags 17..55), single accumulator, exposed tails ====
  // Boundaries: F=24 (straddles t23), F=32 (clean), F=40 (straddles t38),
  // F=48 (straddles t47). Tile nt=12 (t53): only the lower half (feats
  // 384..399) is data-dependent; upper half == onef (handled in D2R).
  s16x8 h1f[25];
  {
    f32x16 a;
    a = vzero; D1MM(17, a)  TAIL1(a, h1f[0],  h1f[1])
    a = vzero; D1MM(20, a)  TAIL1(a, h1f[2],  h1f[3])
    a = vzero;                        // triple (23,24,25) straddles F=24
    __builtin_amdgcn_s_setprio(1);
    a = MFMA(fragF(sm, 23, ln), mf0, a);
    __builtin_amdgcn_s_setprio(0);
    BND(3)                            // F=24: stage P5
    __builtin_amdgcn_s_setprio(1);
    a = MFMA(fragF(sm, 24, ln), mf1, a);
    a = MFMA(fragF(sm, 25, ln), mf2, a);
    __builtin_amdgcn_s_setprio(0);
    TAIL1(a, h1f[4], h1f[5])
    a = vzero; D1MM(26, a)  TAIL1(a, h1f[6],  h1f[7])
    a = vzero; D1MM(29, a)  TAIL1(a, h1f[8],  h1f[9])
    BND(4)                            // F=32 (clean): stage P6
    a = vzero; D1MM(32, a)  TAIL1(a, h1f[10], h1f[11])
    a = vzero; D1MM(35, a)  TAIL1(a, h1f[12], h1f[13])
    a = vzero;                        // triple (38,39,40) straddles F=40
    __builtin_amdgcn_s_setprio(1);
    a = MFMA(fragF(sm, 38, ln), mf0, a);
    a = MFMA(fragF(sm, 39, ln), mf1, a);
    __builtin_amdgcn_s_setprio(0);
    BND(5)                            // F=40: stage P7
    __builtin_amdgcn_s_setprio(1);
    a = MFMA(fragF(sm, 40, ln), mf2, a);
    __builtin_amdgcn_s_setprio(0);
    TAIL1(a, h1f[14], h1f[15])
    a = vzero; D1MM(41, a)  TAIL1(a, h1f[16], h1f[17])
    a = vzero; D1MM(44, a)  TAIL1(a, h1f[18], h1f[19])
    a = vzero;                        // triple (47,48,49) straddles F=48
    __builtin_amdgcn_s_setprio(1);
    a = MFMA(fragF(sm, 47, ln), mf0, a);
    __builtin_amdgcn_s_setprio(0);
    BND(6)                            // F=48: stage P8
    __builtin_amdgcn_s_setprio(1);
    a = MFMA(fragF(sm, 48, ln), mf1, a);
    a = MFMA(fragF(sm, 49, ln), mf2, a);
    __builtin_amdgcn_s_setprio(0);
    TAIL1(a, h1f[20], h1f[21])
    a = vzero; D1MM(50, a)  TAIL1(a, h1f[22], h1f[23])
    a = vzero; D1MM(53, a)
    {                                 // t53: keep only lower half (f1 == onef)
      s16x8 dumm;
      TAIL1(a, h1f[24], dumm)
      (void)dumm;
    }
  }

  // ======== D2/D3 chunks (frags 56..335); chunk n: P0 = 7+7n ========
  f32x16 acc3 = vzero;
  f32x16 d2a0, d2a1;
  CHUNKS(56,  7)
  CHUNKS(112, 14)
  CHUNKS(168, 21)
  CHUNKS(224, 28)
  CHUNKS(280, 35)

  // ---- store: lane (h,c): feat block 8p+4h, regs 4p..4p+3 ----
  float* op = out + (size_t)(rowb + c)*32;
  #pragma unroll
  for (int p = 0; p < 4; ++p){
    float4 v4 = {acc3[4*p+0], acc3[4*p+1], acc3[4*p+2], acc3[4*p+3]};
    *(float4*)(op + p*8 + h*4) = v4;
  }
}

extern "C" void kernel_launch(void* const* d_in, const int* in_sizes, int n_in,
                              void* d_out, int out_size, void* d_ws, size_t ws_size,
                              hipStream_t stream)
{
  const float* state  = (const float*)d_in[0];
  const float* action = (const float*)d_in[1];
  const float* up_w1  = (const float*)d_in[2];
  const float* up_b1  = (const float*)d_in[3];
  const float* up_w2  = (const float*)d_in[4];
  const float* up_b2  = (const float*)d_in[5];
  const float* up_w3  = (const float*)d_in[6];
  const float* up_b3  = (const float*)d_in[7];
  const float* dyn_w1 = (const float*)d_in[8];
  const float* dyn_b1 = (const float*)d_in[9];
  const float* dyn_w2 = (const float*)d_in[10];
  const float* dyn_b2 = (const float*)d_in[11];
  const float* dyn_w3 = (const float*)d_in[12];
  const float* dyn_b3 = (const float*)d_in[13];
  unsigned short* wp = (unsigned short*)d_ws;

  hipLaunchKernelGGL(wconv_kernel, dim3((WS_USHORTS + 255)/256), dim3(256), 0, stream,
                     up_w1, up_b1, up_w2, up_b2, up_w3, up_b3,
                     dyn_w1, dyn_b1, dyn_w2, dyn_b2, dyn_w3, dyn_b3, wp);
  hipLaunchKernelGGL(fused_kernel, dim3(262144/128), dim3(256), 0, stream,
                     state, action, wp, (float*)d_out);
}

// Round 11
// 92.107 us; speedup vs baseline: 2.1834x; 1.2581x over previous
//
#include <hip/hip_runtime.h>
#include <stdint.h>

typedef short s16x8 __attribute__((ext_vector_type(8)));
typedef float f32x16 __attribute__((ext_vector_type(16)));
typedef unsigned int u32;
typedef unsigned int u32x2 __attribute__((ext_vector_type(2)));

#define NFRAG 336
#define WS_USHORTS (NFRAG*512)
#define PANEL_FRAGS 14
#define PANEL_BYTES (PANEL_FRAGS*1024)   // 14336
#define LDS_BYTES (3*PANEL_BYTES)        // 43008

#define MFMA(a,b,c) __builtin_amdgcn_mfma_f32_32x32x16_bf16((a),(b),(c),0,0,0)

__device__ __forceinline__ unsigned short f2bf(float f){
  u32 x = __builtin_bit_cast(u32, f);
  x += 0x7fffu + ((x >> 16) & 1u);   // RNE
  return (unsigned short)(x >> 16);
}

__device__ __forceinline__ float bfhi(float b){
  return __builtin_bit_cast(float, (u32)f2bf(b) << 16);
}

// hot-path pack: single HW instruction, RNE (T12 recipe; no builtin on gfx950)
__device__ __forceinline__ u32 pkbf(float a, float b){
  u32 r;
  asm("v_cvt_pk_bf16_f32 %0, %1, %2" : "=v"(r) : "v"(a), "v"(b));
  return r;
}

__device__ __forceinline__ float fast_tanh(float x){
  float ax = fabsf(x);
  float e = __expf(-2.0f * ax);
  float r = (1.0f - e) * __builtin_amdgcn_rcpf(1.0f + e);
  return x < 0.0f ? -r : r;
}

// cross-half sum. NOTE: do NOT use permlane32_swap(s,s) here — identical
// operands to the in-place two-address swap miscompiled (R1 failure).
__device__ __forceinline__ float halfsum(float s){
  return s + __shfl_xor(s, 32);
}

// D-tile (f32x16: 32 feats x 32 batch) -> two B-frags. permlane32_swap with
// DISTINCT operands (tied-operand hazard cannot occur) — 4 VALU swaps replace
// 8 ds_bpermute + 8 cndmask (R2: +8%).
__device__ __forceinline__ void tile2frags(const f32x16 v, s16x8& f0, s16x8& f1){
  u32 w00 = pkbf(v[0],  v[1]),  w01 = pkbf(v[2],  v[3]);
  u32 w10 = pkbf(v[4],  v[5]),  w11 = pkbf(v[6],  v[7]);
  u32 w20 = pkbf(v[8],  v[9]),  w21 = pkbf(v[10], v[11]);
  u32 w30 = pkbf(v[12], v[13]), w31 = pkbf(v[14], v[15]);
  u32x2 p0 = __builtin_amdgcn_permlane32_swap(w00, w10, false, false);
  u32x2 p1 = __builtin_amdgcn_permlane32_swap(w01, w11, false, false);
  u32x2 p2 = __builtin_amdgcn_permlane32_swap(w20, w30, false, false);
  u32x2 p3 = __builtin_amdgcn_permlane32_swap(w21, w31, false, false);
  int4 r0, r1;
  r0.x = (int)p0[0]; r0.y = (int)p1[0]; r0.z = (int)p0[1]; r0.w = (int)p1[1];
  r1.x = (int)p2[0]; r1.y = (int)p3[0]; r1.z = (int)p2[1]; r1.w = (int)p3[1];
  f0 = __builtin_bit_cast(s16x8, r0);
  f1 = __builtin_bit_cast(s16x8, r1);
}

// ============ weight pre-pack: frag-linear, consumption order, bias hi/lo k-cols ============
// [0,2) L1  [2,12) L2  [12,17) L3  [17,56) D1 (nt-major, 3 kf each)
// [56,336) 5 chunks x 56: r<52 -> D2 frag=kf*2+nt (kf 0..25), r>=52 -> D3 kt=4n+(r-52)
__global__ void wconv_kernel(const float* __restrict__ uw1, const float* __restrict__ ub1,
                             const float* __restrict__ uw2, const float* __restrict__ ub2,
                             const float* __restrict__ uw3, const float* __restrict__ ub3,
                             const float* __restrict__ dw1, const float* __restrict__ db1,
                             const float* __restrict__ dw2, const float* __restrict__ db2,
                             const float* __restrict__ dw3, const float* __restrict__ db3,
                             unsigned short* __restrict__ wp)
{
  int i = blockIdx.x*256 + threadIdx.x;
  if (i >= WS_USHORTS) return;
  int f    = i >> 9;
  int lane = (i >> 3) & 63;
  int j    = i & 7;
  int row  = lane & 31;
  int k8   = (lane >> 5)*8 + j;
  float v = 0.0f;
  if (f < 2){                                   // L1: [x12,u,b_hi,b_lo,0]
    int feat = f*32 + row; int k = k8;
    if (k < 13) v = uw1[feat*13 + k];
    else if (k == 13) v = ub1[feat];
    else if (k == 14) v = ub1[feat] - bfhi(ub1[feat]);
  } else if (f < 12){                           // L2: K=80, k64=b_hi, k65=b_lo
    int t = f - 2; int kt = t >> 1, nt = t & 1;
    int feat = nt*32 + row; int k = kt*16 + k8;
    if (k < 64) v = uw2[feat*128 + k];
    else if (k == 64) v = ub2[feat];
    else if (k == 65) v = ub2[feat] - bfhi(ub2[feat]);
  } else if (f < 17){                           // L3: K=80, k64/65 bias pair
    int kt = f - 12; int feat = row; int k = kt*16 + k8;
    if (k < 64) v = uw3[feat*64 + k];
    else if (k == 64) v = ub3[feat];
    else if (k == 65) v = ub3[feat] - bfhi(ub3[feat]);
  } else if (f < 56){                           // D1: [msg32,u,b_hi,b_lo], K=48
    int t = f - 17; int nt = t/3, kt = t%3;
    int feat = nt*32 + row; int k = kt*16 + k8;
    if (feat < 400){
      if (k < 33) v = dw1[feat*65 + k];
      else if (k == 33) v = db1[feat];
      else if (k == 34) v = db1[feat] - bfhi(db1[feat]);
    } else if ((feat == 400 || feat == 401) && k == 33) v = 1.0f; // h1[400]=h1[401]=1
  } else {                                      // D2/D3 interleaved chunks
    int t = f - 56; int n = t/56; int r = t%56;
    if (r < 52){                                // D2: feat=n*64+nt*32+row, k=kf*16+k8
      int kf = r >> 1, nt = r & 1;
      int feat = n*64 + nt*32 + row; int k = kf*16 + k8;
      if (feat < 300){
        if (k < 400) v = dw2[feat*400 + k];
        else if (k == 400) v = db2[feat];
        else if (k == 401) v = db2[feat] - bfhi(db2[feat]);
      } else if ((feat == 300 || feat == 301) && k == 400) v = 1.0f; // h2[300]=h2[301]=1
    } else {                                    // D3: kt = 4n + (r-52)
      int kt = n*4 + (r - 52); int feat = row; int k = kt*16 + k8;
      if (k < 300) v = dw3[feat*300 + k];
      else if (k == 300) v = db3[feat];
      else if (k == 301) v = db3[feat] - bfhi(db3[feat]);
    }
  }
  wp[i] = f2bf(v);
}

// ============ fused forward: 3-slot 14-frag ring + tail software-pipelining ============
// Proven-best structure (R7, 92.4us). Panel P = frags [14P, 14P+14), slot P%3.
// BND(P): full-drain __syncthreads, then stage panel P+2. Epilogue VALU of
// stage i executes inside stage i+1's barrier regions (dep-free interleave).
// h1f[25] eliminated: D2 kf=25 upper tile == h1 feats 400..415 = (1,1,0,..,0)
// == the onef constant frag (validated R10, identical absmax). Occupancy is
// structurally 2 waves/SIMD: wave state ~200 regs; 3 waves/SIMD needs <=128
// (HW granule, proven by R10's spill) and h1f alone is 100.
__device__ __forceinline__ s16x8 fragF(const char* sm, int f, int ln){
  return *(const s16x8*)(sm + ((f/PANEL_FRAGS) % 3)*PANEL_BYTES
                            + (f % PANEL_FRAGS)*1024 + ln*16);
}

__device__ __forceinline__ void stage14(const unsigned short* wp, char* sm, int panel, int tid){
  char* dst = sm + (panel % 3)*PANEL_BYTES;
  const char* src = (const char*)wp + (size_t)panel*PANEL_BYTES;
  #pragma unroll
  for (int j = 0; j < 3; ++j){
    int off = j*4096 + tid*16;
    __builtin_amdgcn_global_load_lds(
      (const __attribute__((address_space(1))) unsigned int*)(src + off),
      (__attribute__((address_space(3))) unsigned int*)(dst + off), 16, 0, 0);
  }
  int off3 = 12288 + (tid & 127)*16;   // tail 2KB duplicated across half-block (idempotent)
  __builtin_amdgcn_global_load_lds(
    (const __attribute__((address_space(1))) unsigned int*)(src + off3),
    (__attribute__((address_space(3))) unsigned int*)(dst + off3), 16, 0, 0);
}

#define BND(P) { \
  __syncthreads(); \
  if ((P)+2 <= 23) stage14(wp, sm, (P)+2, tid); \
}

// relu in place + pack to two B-frags
#define TAIL1(aSrc, oA, oB) { \
  _Pragma("unroll") \
  for (int r = 0; r < 16; ++r) aSrc[r] = fmaxf(aSrc[r], 0.f); \
  tile2frags(aSrc, oA, oB); }

// 3 MFMAs of one D1 triple into acc (acc pre-zeroed)
#define D1MM(f0_, acc) { \
  __builtin_amdgcn_s_setprio(1); \
  acc = MFMA(fragF(sm, (f0_)+0, ln), mf0, acc); \
  acc = MFMA(fragF(sm, (f0_)+1, ln), mf1, acc); \
  acc = MFMA(fragF(sm, (f0_)+2, ln), mf2, acc); \
  __builtin_amdgcn_s_setprio(0); }

// D2 MFMA run [r0,r1); kf==25 (r=50,51) uses the constant onef frag
#define D2R(fb, r0, r1, A0, A1) { \
  __builtin_amdgcn_s_setprio(1); \
  _Pragma("unroll") \
  for (int r = (r0); r < (r1); ++r){ \
    s16x8 hb = ((r>>1) == 25) ? onef : h1f[r>>1]; \
    if (r & 1) A1 = MFMA(fragF(sm, (fb)+r, ln), hb, A1); \
    else       A0 = MFMA(fragF(sm, (fb)+r, ln), hb, A0); \
  } \
  __builtin_amdgcn_s_setprio(0); }

// pre-read D3 weight frags (fb+52..55) into registers before their panel dies
#define LOADD3W(fb) { \
  d3w0 = fragF(sm, (fb)+52, ln); \
  d3w1 = fragF(sm, (fb)+53, ln); \
  d3w2 = fragF(sm, (fb)+54, ln); \
  d3w3 = fragF(sm, (fb)+55, ln); }

// deferred chunk tail, split into pieces placed in successive regions
#define TAILD2_RELU(A0, A1) { \
  _Pragma("unroll") \
  for (int r = 0; r < 16; ++r){ \
    A0[r] = fmaxf(A0[r], 0.f); \
    A1[r] = fmaxf(A1[r], 0.f); \
  } }
#define TAILD2_CVT(A0, A1) { \
  tile2frags(A0, cT0, cT1); \
  tile2frags(A1, cT2, cT3); }
#define TAILD2_D3() { \
  __builtin_amdgcn_s_setprio(1); \
  acc3 = MFMA(d3w0, cT0, acc3); \
  acc3 = MFMA(d3w1, cT1, acc3); \
  acc3 = MFMA(d3w2, cT2, acc3); \
  acc3 = MFMA(d3w3, cT3, acc3); \
  __builtin_amdgcn_s_setprio(0); }

// chunk n>=1: run CUR accumulation while retiring PRV's tail
#define CHUNKN(fb, P0, C0_, C1_, PR0, PR1) { \
  BND(P0) \
  C0_ = vzero; C1_ = vzero; \
  D2R(fb, 0, 14, C0_, C1_) \
  TAILD2_RELU(PR0, PR1) \
  BND((P0)+1) \
  D2R(fb, 14, 28, C0_, C1_) \
  TAILD2_CVT(PR0, PR1) \
  BND((P0)+2) \
  D2R(fb, 28, 42, C0_, C1_) \
  TAILD2_D3() \
  BND((P0)+3) \
  D2R(fb, 42, 52, C0_, C1_) \
  LOADD3W(fb) \
}

__global__ __launch_bounds__(256, 2) void fused_kernel(
    const float* __restrict__ state, const float* __restrict__ action,
    const unsigned short* __restrict__ wp, float* __restrict__ out)
{
  __shared__ __align__(1024) char sm[LDS_BYTES];

  const int tid = threadIdx.x;
  const int ln  = tid & 63;
  const int wid = tid >> 6;
  const int c   = ln & 31;          // batch col within wave
  const int h   = ln >> 5;          // lane half
  const int rowb = blockIdx.x*128 + wid*32;

  const f32x16 vzero = {};

  // ---- issue x/u loads (latency hides under P0/P1 staging) ----
  const float* xr = state + (size_t)(rowb + c)*12;
  float u = action[rowb + c];
  float4 xa, xbr;
  if (h == 0){
    xa  = *(const float4*)xr;
    xbr = *(const float4*)(xr + 4);
  } else {
    xa  = *(const float4*)(xr + 8);
  }

  stage14(wp, sm, 0, tid);
  stage14(wp, sm, 1, tid);
  BND(0)                                // publish P0+P1; stage P2

  // ---- pack constants (overlaps P2 staging) ----
  float4 xb = (h == 0) ? xbr : float4{u, 1.0f, 1.0f, 0.0f}; // k12=u, k13/14 bias carriers
  int4 xw;
  xw.x = pkbf(xa.x, xa.y); xw.y = pkbf(xa.z, xa.w);
  xw.z = pkbf(xb.x, xb.y); xw.w = pkbf(xb.z, xb.w);
  s16x8 xfrag = __builtin_bit_cast(s16x8, xw);
  int4 ow = {0,0,0,0}; if (h == 0) ow.x = 0x3F803F80;   // slots 0,1 = 1.0 @ h=0
  s16x8 onef = __builtin_bit_cast(s16x8, ow);
  int4 mw = {0,0,0,0};
  if (h == 0){ mw.x = pkbf(u, 1.0f); mw.y = 0x3F80; }   // k32=u, k33=1, k34=1
  s16x8 mf2 = __builtin_bit_cast(s16x8, mw);

  // ======== C0: up-net (frags 0..16); boundary F=14 splits the L3 group ========
  s16x8 mf0, mf1;
  {
    s16x8 xf0, xf1, xf2, xf3, tf0, tf1, tf2, tf3;
    {
      f32x16 a0 = {}, a1 = {};
      a0 = MFMA(fragF(sm, 0, ln), xfrag, a0);
      a1 = MFMA(fragF(sm, 1, ln), xfrag, a1);
      float s = 0.f;
      #pragma unroll
      for (int r = 0; r < 16; ++r) s += a0[r]*a0[r] + a1[r]*a1[r];
      s = halfsum(s);
      float inv = __builtin_amdgcn_rsqf(fmaxf(s, 1e-24f));
      #pragma unroll
      for (int r = 0; r < 16; ++r){
        a0[r] = fast_tanh(a0[r]*inv);
        a1[r] = fast_tanh(a1[r]*inv);
      }
      tile2frags(a0, xf0, xf1);
      tile2frags(a1, xf2, xf3);
    }
    {
      f32x16 a0 = {}, a1 = {};
      __builtin_amdgcn_s_setprio(1);
      a0 = MFMA(fragF(sm, 2, ln), xf0, a0);  a1 = MFMA(fragF(sm, 3, ln), xf0, a1);
      a0 = MFMA(fragF(sm, 4, ln), xf1, a0);  a1 = MFMA(fragF(sm, 5, ln), xf1, a1);
      a0 = MFMA(fragF(sm, 6, ln), xf2, a0);  a1 = MFMA(fragF(sm, 7, ln), xf2, a1);
      a0 = MFMA(fragF(sm, 8, ln), xf3, a0);  a1 = MFMA(fragF(sm, 9, ln), xf3, a1);
      a0 = MFMA(fragF(sm,10, ln), onef, a0); a1 = MFMA(fragF(sm,11, ln), onef, a1);
      __builtin_amdgcn_s_setprio(0);
      #pragma unroll
      for (int r = 0; r < 16; ++r){
        a0[r] = fast_tanh(a0[r]);
        a1[r] = fast_tanh(a1[r]);
      }
      tile2frags(a0, tf0, tf1);
      tile2frags(a1, tf2, tf3);
    }
    {
      f32x16 m = {};
      __builtin_amdgcn_s_setprio(1);
      m = MFMA(fragF(sm,12, ln), tf0, m);
      m = MFMA(fragF(sm,13, ln), tf1, m);
      __builtin_amdgcn_s_setprio(0);
      BND(1)                            // F=14: publish P1; stage P3
      __builtin_amdgcn_s_setprio(1);
      m = MFMA(fragF(sm,14, ln), tf2, m);
      m = MFMA(fragF(sm,15, ln), tf3, m);
      m = MFMA(fragF(sm,16, ln), onef, m);
      __builtin_amdgcn_s_setprio(0);
      float s = 0.f;
      #pragma unroll
      for (int r = 0; r < 16; ++r) s += m[r]*m[r];
      s = halfsum(s);
      float inv = __builtin_amdgcn_rsqf(fmaxf(s, 1e-24f));
      #pragma unroll
      for (int r = 0; r < 16; ++r) m[r] *= inv;
      tile2frags(m, mf0, mf1);
    }
  }

  // ======== D1: 13 triples (frags 17..55), tail-pipelined via aX/aY ========
  // Tail of triple i runs inside triple i+1's region (dep-free interleave).
  s16x8 h1f[25];
  f32x16 aX = vzero, aY = vzero;
  D1MM(17, aX)
  D1MM(20, aY)  TAIL1(aX, h1f[0],  h1f[1])
  aX = vzero; D1MM(23, aX)  TAIL1(aY, h1f[2],  h1f[3])
  aY = vzero;                         // triple (26,27,28) straddles F=28
  __builtin_amdgcn_s_setprio(1);
  aY = MFMA(fragF(sm, 26, ln), mf0, aY);
  aY = MFMA(fragF(sm, 27, ln), mf1, aY);
  __builtin_amdgcn_s_setprio(0);
  BND(2)                              // F=28: stage P4
  __builtin_amdgcn_s_setprio(1);
  aY = MFMA(fragF(sm, 28, ln), mf2, aY);
  __builtin_amdgcn_s_setprio(0);
  TAIL1(aX, h1f[4], h1f[5])
  aX = vzero; D1MM(29, aX)  TAIL1(aY, h1f[6],  h1f[7])
  aY = vzero; D1MM(32, aY)  TAIL1(aX, h1f[8],  h1f[9])
  aX = vzero; D1MM(35, aX)  TAIL1(aY, h1f[10], h1f[11])
  aY = vzero; D1MM(38, aY)  TAIL1(aX, h1f[12], h1f[13])
  aX = vzero;                         // triple (41,42,43) straddles F=42
  __builtin_amdgcn_s_setprio(1);
  aX = MFMA(fragF(sm, 41, ln), mf0, aX);
  __builtin_amdgcn_s_setprio(0);
  BND(3)                              // F=42: stage P5
  __builtin_amdgcn_s_setprio(1);
  aX = MFMA(fragF(sm, 42, ln), mf1, aX);
  aX = MFMA(fragF(sm, 43, ln), mf2, aX);
  __builtin_amdgcn_s_setprio(0);
  TAIL1(aY, h1f[14], h1f[15])
  aY = vzero; D1MM(44, aY)  TAIL1(aX, h1f[16], h1f[17])
  aX = vzero; D1MM(47, aX)  TAIL1(aY, h1f[18], h1f[19])
  aY = vzero; D1MM(50, aY)  TAIL1(aX, h1f[20], h1f[21])
  aX = vzero; D1MM(53, aX)  TAIL1(aY, h1f[22], h1f[23])
  // aX = triple 53; its tail retires inside chunk0's first region. Only the
  // lower half (h1 feats 384..399) is data-dependent; the upper half == onef.

  // ======== D2/D3 chunks (frags 56..335), chunk tails pipelined ========
  f32x16 acc3 = vzero;
  f32x16 dA0, dA1, dB0, dB1;
  s16x8 d3w0, d3w1, d3w2, d3w3, cT0, cT1, cT2, cT3;

  {                                   // chunk0 (fb=56, P0=4) -> dA; D1-t53 tail inside
    BND(4)
    dA0 = vzero; dA1 = vzero;
    D2R(56, 0, 14, dA0, dA1)
    {
      s16x8 dumm;
      TAIL1(aX, h1f[24], dumm)
      (void)dumm;                     // upper half == onef, never materialized
    }
    BND(5)
    D2R(56, 14, 28, dA0, dA1)
    BND(6)
    D2R(56, 28, 42, dA0, dA1)
    BND(7)
    D2R(56, 42, 52, dA0, dA1)
    LOADD3W(56)
  }
  CHUNKN(112,  8, dB0, dB1, dA0, dA1)   // chunk1 -> dB; retires chunk0 (dA)
  CHUNKN(168, 12, dA0, dA1, dB0, dB1)   // chunk2 -> dA; retires chunk1 (dB)
  CHUNKN(224, 16, dB0, dB1, dA0, dA1)   // chunk3 -> dB; retires chunk2 (dA)
  CHUNKN(280, 20, dA0, dA1, dB0, dB1)   // chunk4 -> dA; retires chunk3 (dB)
  // final tail: chunk4 (dA), exposed once
  TAILD2_RELU(dA0, dA1)
  TAILD2_CVT(dA0, dA1)
  TAILD2_D3()

  // ---- store: lane (h,c): feat block 8p+4h, regs 4p..4p+3 ----
  float* op = out + (size_t)(rowb + c)*32;
  #pragma unroll
  for (int p = 0; p < 4; ++p){
    float4 v4 = {acc3[4*p+0], acc3[4*p+1], acc3[4*p+2], acc3[4*p+3]};
    *(float4*)(op + p*8 + h*4) = v4;
  }
}

extern "C" void kernel_launch(void* const* d_in, const int* in_sizes, int n_in,
                              void* d_out, int out_size, void* d_ws, size_t ws_size,
                              hipStream_t stream)
{
  const float* state  = (const float*)d_in[0];
  const float* action = (const float*)d_in[1];
  const float* up_w1  = (const float*)d_in[2];
  const float* up_b1  = (const float*)d_in[3];
  const float* up_w2  = (const float*)d_in[4];
  const float* up_b2  = (const float*)d_in[5];
  const float* up_w3  = (const float*)d_in[6];
  const float* up_b3  = (const float*)d_in[7];
  const float* dyn_w1 = (const float*)d_in[8];
  const float* dyn_b1 = (const float*)d_in[9];
  const float* dyn_w2 = (const float*)d_in[10];
  const float* dyn_b2 = (const float*)d_in[11];
  const float* dyn_w3 = (const float*)d_in[12];
  const float* dyn_b3 = (const float*)d_in[13];
  unsigned short* wp = (unsigned short*)d_ws;

  hipLaunchKernelGGL(wconv_kernel, dim3((WS_USHORTS + 255)/256), dim3(256), 0, stream,
                     up_w1, up_b1, up_w2, up_b2, up_w3, up_b3,
                     dyn_w1, dyn_b1, dyn_w2, dyn_b2, dyn_w3, dyn_b3, wp);
  hipLaunchKernelGGL(fused_kernel, dim3(262144/128), dim3(256), 0, stream,
                     state, action, wp, (float*)d_out);
}